// Round 5
// baseline (241.641 us; speedup 1.0000x reference)
//
#include <hip/hip_runtime.h>

#define BATCH 8
#define SEQ   2048
#define EMB   1024
#define HD    64
#define HEADS 16
#define LOG2E 1.4426950408889634f

typedef _Float16 half8 __attribute__((ext_vector_type(8)));
typedef _Float16 half4 __attribute__((ext_vector_type(4)));
typedef float    f32x4 __attribute__((ext_vector_type(4)));

__device__ __forceinline__ float fexp2(float x) {
#if __has_builtin(__builtin_amdgcn_exp2f)
    return __builtin_amdgcn_exp2f(x);
#else
    return exp2f(x);
#endif
}

// ---------------- W -> fp16 (Wq pre-scaled by log2e: scores in log2 domain)
__global__ __launch_bounds__(256) void wcvt_kernel(
    const float* __restrict__ Wq, const float* __restrict__ Wk,
    const float* __restrict__ Wv, _Float16* __restrict__ Wh)
{
    const int m = blockIdx.y;
    const float* src = (m == 0) ? Wq : (m == 1) ? Wk : Wv;
    const float scale = (m == 0) ? LOG2E : 1.0f;
    const int idx = (blockIdx.x * 256 + threadIdx.x) * 8;   // < 65536
    float4 f0 = *(const float4*)(src + idx);
    float4 f1 = *(const float4*)(src + idx + 4);
    half8 h;
    h[0] = (_Float16)(f0.x * scale); h[1] = (_Float16)(f0.y * scale);
    h[2] = (_Float16)(f0.z * scale); h[3] = (_Float16)(f0.w * scale);
    h[4] = (_Float16)(f1.x * scale); h[5] = (_Float16)(f1.y * scale);
    h[6] = (_Float16)(f1.z * scale); h[7] = (_Float16)(f1.w * scale);
    *(half8*)(Wh + (size_t)m * 65536 + idx) = h;
}

// ---------------- QKV projection ----------------
// 512 blocks x 512 thr (8 waves). Block = 32 rows, all 3 matrices (12 ctiles).
// wave: strip=(w&1) -> 16 rows; grp=(w>>1) -> 3 ctiles.  x staged to LDS fp16
// with depth-2 register prefetch, double-buffered, 1 barrier/chunk.
__global__ __launch_bounds__(512, 4) void qkv_kernel(
    const float* __restrict__ x, const _Float16* __restrict__ Wh,
    _Float16* __restrict__ qh, _Float16* __restrict__ kh, _Float16* __restrict__ vpt)
{
    __shared__ _Float16 xs[2][32][72];   // 32 rows x 64 halves, pad to 72
    const int t = threadIdx.x, lane = t & 63, wave = t >> 6;
    const int l15 = lane & 15, quad = lane >> 4;
    const int strip = wave & 1, grp = wave >> 1;   // grp 0..3
    const int row0 = blockIdx.x * 32;
    const int srow = t >> 4, sseg = t & 15;        // staging: 1 float4 / thread

    const float* __restrict__ xp = x + (size_t)(row0 + srow) * EMB + sseg * 4;

    float4 xr[2];
    xr[0] = *(const float4*)(xp);          // chunk 0
    xr[1] = *(const float4*)(xp + 64);     // chunk 1
    {   // stage chunk 0
        half4 h;
        h[0] = (_Float16)xr[0].x; h[1] = (_Float16)xr[0].y;
        h[2] = (_Float16)xr[0].z; h[3] = (_Float16)xr[0].w;
        *(half4*)&xs[0][srow][sseg * 4] = h;
    }
    __syncthreads();

    f32x4 acc[3] = {};
    #pragma unroll
    for (int it = 0; it < 16; ++it) {
        if (it + 2 < 16) xr[it & 1] = *(const float4*)(xp + (it + 2) * 64);
        // compute chunk it
        half8 a0 = *(half8*)&xs[it & 1][strip * 16 + l15][quad * 8];
        half8 a1 = *(half8*)&xs[it & 1][strip * 16 + l15][32 + quad * 8];
        #pragma unroll
        for (int j = 0; j < 3; ++j) {
            int c = grp * 3 + j, m = c >> 2, n = c & 3;
            const _Float16* wp = Wh + (size_t)m * 65536
                               + (size_t)(n * 16 + l15) * EMB + it * 64 + quad * 8;
            half8 b0 = *(const half8*)(wp);
            half8 b1 = *(const half8*)(wp + 32);
            acc[j] = __builtin_amdgcn_mfma_f32_16x16x32_f16(a0, b0, acc[j], 0, 0, 0);
            acc[j] = __builtin_amdgcn_mfma_f32_16x16x32_f16(a1, b1, acc[j], 0, 0, 0);
        }
        if (it + 1 < 16) {   // stage chunk it+1 from the reg loaded 2 iters ago
            float4 v = xr[(it + 1) & 1];
            half4 h;
            h[0] = (_Float16)v.x; h[1] = (_Float16)v.y;
            h[2] = (_Float16)v.z; h[3] = (_Float16)v.w;
            *(half4*)&xs[(it + 1) & 1][srow][sseg * 4] = h;
        }
        __syncthreads();
    }

    #pragma unroll
    for (int j = 0; j < 3; ++j) {
        int c = grp * 3 + j, m = c >> 2, n = c & 3;
        if (m < 2) {
            _Float16* __restrict__ dst = (m == 0) ? qh : kh;
            #pragma unroll
            for (int r = 0; r < 4; ++r)
                dst[(size_t)(row0 + strip * 16 + quad * 4 + r) * HD + n * 16 + l15] =
                    (_Float16)acc[j][r];
        } else {
            const int rg = row0 + strip * 16 + quad * 4;
            const int b = rg >> 11, s = rg & 2047;
            half4 h;
            h[0] = (_Float16)acc[j][0]; h[1] = (_Float16)acc[j][1];
            h[2] = (_Float16)acc[j][2]; h[3] = (_Float16)acc[j][3];
            *(half4*)(vpt + ((size_t)b * HD + n * 16 + l15) * SEQ + s) = h;
        }
    }
}

// ---------------- Column-softmax denominators ----------------
// grid (128, 8) x 256 thr (4 waves). Block = 16 keys; wave w sweeps queries
// [w*512,(w+1)*512) in 32 chunks of 16, depth-2 prefetch.  A = keys (held),
// B = queries (streamed): C[key=quad*4+r][query=l15]; 4 exp/lane/chunk.
__global__ __launch_bounds__(256, 4) void stats_kernel(
    const _Float16* __restrict__ qh, const _Float16* __restrict__ kh,
    float* __restrict__ l_inv)
{
    __shared__ float red[4][16];
    const int t = threadIdx.x, lane = t & 63, wave = t >> 6;
    const int l15 = lane & 15, quad = lane >> 4;
    const int b = blockIdx.y, c0 = blockIdx.x * 16;

    half8 ka[2];
    {
        const _Float16* kp = kh + ((size_t)b * SEQ + c0 + l15) * HD + quad * 8;
        ka[0] = *(const half8*)(kp);
        ka[1] = *(const half8*)(kp + 32);
    }
    const _Float16* __restrict__ qb =
        qh + ((size_t)b * SEQ + wave * 512 + l15) * HD + quad * 8;

    half8 qa[2][2];
    qa[0][0] = *(const half8*)(qb);
    qa[0][1] = *(const half8*)(qb + 32);
    qa[1][0] = *(const half8*)(qb + 16 * HD);
    qa[1][1] = *(const half8*)(qb + 16 * HD + 32);

    float csum[4] = {};
    #pragma unroll
    for (int it = 0; it < 32; ++it) {
        f32x4 s = {};
        s = __builtin_amdgcn_mfma_f32_16x16x32_f16(ka[0], qa[it & 1][0], s, 0, 0, 0);
        s = __builtin_amdgcn_mfma_f32_16x16x32_f16(ka[1], qa[it & 1][1], s, 0, 0, 0);
        const int nx = (it + 2 < 32) ? it + 2 : it;   // clamped prefetch
        qa[it & 1][0] = *(const half8*)(qb + (size_t)nx * 16 * HD);
        qa[it & 1][1] = *(const half8*)(qb + (size_t)nx * 16 * HD + 32);
        #pragma unroll
        for (int r = 0; r < 4; ++r) csum[r] += fexp2(s[r]);
    }
    #pragma unroll
    for (int r = 0; r < 4; ++r) {   // butterfly over l15 (16-lane groups)
        csum[r] += __shfl_xor(csum[r], 1);
        csum[r] += __shfl_xor(csum[r], 2);
        csum[r] += __shfl_xor(csum[r], 4);
        csum[r] += __shfl_xor(csum[r], 8);
    }
    if (l15 == 0) {
        #pragma unroll
        for (int r = 0; r < 4; ++r) red[wave][quad * 4 + r] = csum[r];
    }
    __syncthreads();
    if (t < 16)
        l_inv[(size_t)b * SEQ + c0 + t] =
            1.0f / (red[0][t] + red[1][t] + red[2][t] + red[3][t]);
}

// ---------------- out = P~ @ v, P~ = exp2(s~)*l_inv[key] (fp16) ----------------
// grid (128, 8) x 256 thr (4 waves). Block = 16 q-rows; wave w owns keys
// [w*512,(w+1)*512), 8 chunks of 64. Barrier-free main loop (wave-private P).
// LDS cross-wave O reduction + x16-head coalesced epilogue.
__global__ __launch_bounds__(256, 3) void out_kernel(
    const _Float16* __restrict__ qh, const _Float16* __restrict__ kh,
    const _Float16* __restrict__ vpt, const float* __restrict__ l_inv,
    float* __restrict__ out)
{
    __shared__ _Float16 ps[4][16][72];   // wave-private P~ tiles
    __shared__ float red[3][16][68];     // cross-wave partials; red[0] reused as final
    const int t = threadIdx.x, lane = t & 63, wave = t >> 6;
    const int l15 = lane & 15, quad = lane >> 4;
    const int b = blockIdx.y, r0 = blockIdx.x * 16;

    half8 aq[2];
    {
        const _Float16* qp = qh + ((size_t)b * SEQ + r0 + l15) * HD + quad * 8;
        aq[0] = *(const half8*)(qp);
        aq[1] = *(const half8*)(qp + 32);
    }

    f32x4 oacc[4] = {};
    const int kq0 = wave * 512;
    #pragma unroll 2
    for (int it = 0; it < 8; ++it) {
        const int c0 = kq0 + it * 64;
        float li[4];
        half8 kb[4][2];
        #pragma unroll
        for (int ct = 0; ct < 4; ++ct) {
            li[ct] = l_inv[(size_t)b * SEQ + c0 + ct * 16 + l15];
            const _Float16* kp = kh + ((size_t)b * SEQ + c0 + ct * 16 + l15) * HD + quad * 8;
            kb[ct][0] = *(const half8*)(kp);
            kb[ct][1] = *(const half8*)(kp + 32);
        }
        f32x4 s[4] = {};
        #pragma unroll
        for (int kc = 0; kc < 2; ++kc)
            #pragma unroll
            for (int ct = 0; ct < 4; ++ct)
                s[ct] = __builtin_amdgcn_mfma_f32_16x16x32_f16(aq[kc], kb[ct][kc], s[ct], 0, 0, 0);
        half8 vb[4][2];   // issue v loads before the exp/LDS phase for latency cover
        #pragma unroll
        for (int n = 0; n < 4; ++n) {
            const _Float16* vp = vpt + ((size_t)b * HD + n * 16 + l15) * SEQ + c0 + quad * 8;
            vb[n][0] = *(const half8*)(vp);
            vb[n][1] = *(const half8*)(vp + 32);
        }
        #pragma unroll
        for (int ct = 0; ct < 4; ++ct)
            #pragma unroll
            for (int r = 0; r < 4; ++r)
                ps[wave][quad * 4 + r][ct * 16 + l15] =
                    (_Float16)(fexp2(s[ct][r]) * li[ct]);
        half8 pa[2];
        pa[0] = *(half8*)&ps[wave][l15][quad * 8];
        pa[1] = *(half8*)&ps[wave][l15][32 + quad * 8];
        #pragma unroll
        for (int kc = 0; kc < 2; ++kc)
            #pragma unroll
            for (int n = 0; n < 4; ++n)
                oacc[n] = __builtin_amdgcn_mfma_f32_16x16x32_f16(pa[kc], vb[n][kc], oacc[n], 0, 0, 0);
    }

    // cross-wave reduction: waves 1..3 dump, wave 0 accumulates -> red[0]
    if (wave > 0) {
        #pragma unroll
        for (int n = 0; n < 4; ++n)
            #pragma unroll
            for (int r = 0; r < 4; ++r)
                red[wave - 1][quad * 4 + r][n * 16 + l15] = oacc[n][r];
    }
    __syncthreads();
    if (wave == 0) {
        #pragma unroll
        for (int n = 0; n < 4; ++n)
            #pragma unroll
            for (int r = 0; r < 4; ++r) {
                float v = oacc[n][r]
                        + red[0][quad * 4 + r][n * 16 + l15]
                        + red[1][quad * 4 + r][n * 16 + l15]
                        + red[2][quad * 4 + r][n * 16 + l15];
                red[0][quad * 4 + r][n * 16 + l15] = v;
            }
    }
    __syncthreads();

    // epilogue: 16x64 f32 tile -> 16 head slots, coalesced float4
    const int row = t >> 4, seg = t & 15;
    float4 u = *(float4*)&red[0][row][seg * 4];
    size_t base = ((size_t)b * SEQ + r0 + row) * (HD * HEADS);
    #pragma unroll
    for (int h = 0; h < HEADS; ++h)
        *(float4*)&out[base + h * HD + seg * 4] = u;
}

extern "C" void kernel_launch(void* const* d_in, const int* in_sizes, int n_in,
                              void* d_out, int out_size, void* d_ws, size_t ws_size,
                              hipStream_t stream)
{
    const float* x  = (const float*)d_in[0];
    const float* Wq = (const float*)d_in[1];
    const float* Wk = (const float*)d_in[2];
    const float* Wv = (const float*)d_in[3];
    float* out = (float*)d_out;

    const size_t N = (size_t)BATCH * SEQ * HD;   // 1,048,576
    _Float16* qh  = (_Float16*)d_ws;
    _Float16* kh  = qh + N;
    _Float16* vpt = kh + N;
    _Float16* Wh  = vpt + N;                     // 3*64*1024 = 196608 halves
    float* l_inv  = (float*)(Wh + 196608);       // 16384 floats

    wcvt_kernel <<<dim3(32, 3),   256, 0, stream>>>(Wq, Wk, Wv, Wh);
    qkv_kernel  <<<dim3(512),     512, 0, stream>>>(x, Wh, qh, kh, vpt);
    stats_kernel<<<dim3(128, 8),  256, 0, stream>>>(qh, kh, l_inv);
    out_kernel  <<<dim3(128, 8),  256, 0, stream>>>(qh, kh, vpt, l_inv, out);
}

// Round 6
// 237.357 us; speedup vs baseline: 1.0180x; 1.0180x over previous
//
#include <hip/hip_runtime.h>

#define BATCH 8
#define SEQ   2048
#define EMB   1024
#define HD    64
#define HEADS 16
#define LOG2E 1.4426950408889634f

typedef _Float16 half8 __attribute__((ext_vector_type(8)));
typedef _Float16 half4 __attribute__((ext_vector_type(4)));
typedef float    f32x4 __attribute__((ext_vector_type(4)));

__device__ __forceinline__ float fexp2(float x) {
#if __has_builtin(__builtin_amdgcn_exp2f)
    return __builtin_amdgcn_exp2f(x);
#else
    return exp2f(x);
#endif
}

// ---------------- W -> fp16 (Wq pre-scaled by log2e: scores in log2 domain)
__global__ __launch_bounds__(256) void wcvt_kernel(
    const float* __restrict__ Wq, const float* __restrict__ Wk,
    const float* __restrict__ Wv, _Float16* __restrict__ Wh)
{
    const int m = blockIdx.y;
    const float* src = (m == 0) ? Wq : (m == 1) ? Wk : Wv;
    const float scale = (m == 0) ? LOG2E : 1.0f;
    const int idx = (blockIdx.x * 256 + threadIdx.x) * 8;   // < 65536
    float4 f0 = *(const float4*)(src + idx);
    float4 f1 = *(const float4*)(src + idx + 4);
    half8 h;
    h[0] = (_Float16)(f0.x * scale); h[1] = (_Float16)(f0.y * scale);
    h[2] = (_Float16)(f0.z * scale); h[3] = (_Float16)(f0.w * scale);
    h[4] = (_Float16)(f1.x * scale); h[5] = (_Float16)(f1.y * scale);
    h[6] = (_Float16)(f1.z * scale); h[7] = (_Float16)(f1.w * scale);
    *(half8*)(Wh + (size_t)m * 65536 + idx) = h;
}

// ---------------- QKV projection ----------------
// 512 blocks x 512 thr (8 waves). Block = 32 rows, 12 ctiles (3 matrices x 4 ntiles).
// wave: strip=(w&1) -> 16 rows; grp=(w>>1) -> 3 ctiles.
// x: LDS double-buffer w/ depth-2 reg prefetch. W: depth-1 reg prefetch from L2.
__global__ __launch_bounds__(512, 4) void qkv_kernel(
    const float* __restrict__ x, const _Float16* __restrict__ Wh,
    _Float16* __restrict__ qh, _Float16* __restrict__ kh, _Float16* __restrict__ vpt)
{
    __shared__ _Float16 xs[2][32][72];
    const int t = threadIdx.x, lane = t & 63, wave = t >> 6;
    const int l15 = lane & 15, quad = lane >> 4;
    const int strip = wave & 1, grp = wave >> 1;   // grp 0..3
    const int row0 = blockIdx.x * 32;
    const int srow = t >> 4, sseg = t & 15;        // staging: 1 float4 / thread

    const float* __restrict__ xp = x + (size_t)(row0 + srow) * EMB + sseg * 4;

    // W base pointers for this wave's 3 ctiles
    const _Float16* wpb[3];
    int mj[3], nj[3];
    #pragma unroll
    for (int j = 0; j < 3; ++j) {
        int c = grp * 3 + j; mj[j] = c >> 2; nj[j] = c & 3;
        wpb[j] = Wh + (size_t)mj[j] * 65536 + (size_t)(nj[j] * 16 + l15) * EMB + quad * 8;
    }

    float4 xr[2];
    xr[0] = *(const float4*)(xp);
    xr[1] = *(const float4*)(xp + 64);
    {
        half4 h;
        h[0] = (_Float16)xr[0].x; h[1] = (_Float16)xr[0].y;
        h[2] = (_Float16)xr[0].z; h[3] = (_Float16)xr[0].w;
        *(half4*)&xs[0][srow][sseg * 4] = h;
    }
    half8 wb[2][3][2];
    #pragma unroll
    for (int j = 0; j < 3; ++j) {
        wb[0][j][0] = *(const half8*)(wpb[j]);
        wb[0][j][1] = *(const half8*)(wpb[j] + 32);
    }
    __syncthreads();

    f32x4 acc[3] = {};
    #pragma unroll 2
    for (int it = 0; it < 16; ++it) {
        if (it + 2 < 16) xr[it & 1] = *(const float4*)(xp + (it + 2) * 64);
        if (it + 1 < 16) {   // prefetch next W chunk
            #pragma unroll
            for (int j = 0; j < 3; ++j) {
                wb[(it + 1) & 1][j][0] = *(const half8*)(wpb[j] + (it + 1) * 64);
                wb[(it + 1) & 1][j][1] = *(const half8*)(wpb[j] + (it + 1) * 64 + 32);
            }
        }
        half8 a0 = *(half8*)&xs[it & 1][strip * 16 + l15][quad * 8];
        half8 a1 = *(half8*)&xs[it & 1][strip * 16 + l15][32 + quad * 8];
        #pragma unroll
        for (int j = 0; j < 3; ++j) {
            acc[j] = __builtin_amdgcn_mfma_f32_16x16x32_f16(a0, wb[it & 1][j][0], acc[j], 0, 0, 0);
            acc[j] = __builtin_amdgcn_mfma_f32_16x16x32_f16(a1, wb[it & 1][j][1], acc[j], 0, 0, 0);
        }
        if (it + 1 < 16) {
            float4 v = xr[(it + 1) & 1];
            half4 h;
            h[0] = (_Float16)v.x; h[1] = (_Float16)v.y;
            h[2] = (_Float16)v.z; h[3] = (_Float16)v.w;
            *(half4*)&xs[(it + 1) & 1][srow][sseg * 4] = h;
        }
        __syncthreads();
    }

    #pragma unroll
    for (int j = 0; j < 3; ++j) {
        if (mj[j] < 2) {
            _Float16* __restrict__ dst = (mj[j] == 0) ? qh : kh;
            #pragma unroll
            for (int r = 0; r < 4; ++r)
                dst[(size_t)(row0 + strip * 16 + quad * 4 + r) * HD + nj[j] * 16 + l15] =
                    (_Float16)acc[j][r];
        } else {
            const int rg = row0 + strip * 16 + quad * 4;
            const int b = rg >> 11, s = rg & 2047;
            half4 h;
            h[0] = (_Float16)acc[j][0]; h[1] = (_Float16)acc[j][1];
            h[2] = (_Float16)acc[j][2]; h[3] = (_Float16)acc[j][3];
            *(half4*)(vpt + ((size_t)b * HD + nj[j] * 16 + l15) * SEQ + s) = h;
        }
    }
}

// ---------------- Column-softmax denominators ----------------
// grid (SEQ/32=64, 8) x 512 thr (8 waves). Block = 32 keys (A-frags held).
// wave w sweeps queries [w*256,(w+1)*256) in 16 chunks of 16, depth-4 prefetch.
// C[key=quad*4+r][query=l15]; 8 exp/lane/chunk.
__global__ __launch_bounds__(512, 4) void stats_kernel(
    const _Float16* __restrict__ qh, const _Float16* __restrict__ kh,
    float* __restrict__ l_inv)
{
    __shared__ float red[8][32];
    const int t = threadIdx.x, lane = t & 63, wave = t >> 6;
    const int l15 = lane & 15, quad = lane >> 4;
    const int b = blockIdx.y, c0 = blockIdx.x * 32;

    half8 ka[2][2];
    #pragma unroll
    for (int kt = 0; kt < 2; ++kt) {
        const _Float16* kp = kh + ((size_t)b * SEQ + c0 + kt * 16 + l15) * HD + quad * 8;
        ka[kt][0] = *(const half8*)(kp);
        ka[kt][1] = *(const half8*)(kp + 32);
    }
    const _Float16* __restrict__ qb =
        qh + ((size_t)b * SEQ + wave * 256 + l15) * HD + quad * 8;

    half8 qa[4][2];
    #pragma unroll
    for (int p = 0; p < 4; ++p) {
        qa[p][0] = *(const half8*)(qb + (size_t)p * 16 * HD);
        qa[p][1] = *(const half8*)(qb + (size_t)p * 16 * HD + 32);
    }

    float csum[2][4] = {};
    #pragma unroll
    for (int it = 0; it < 16; ++it) {
        f32x4 s0 = {}, s1 = {};
        s0 = __builtin_amdgcn_mfma_f32_16x16x32_f16(ka[0][0], qa[it & 3][0], s0, 0, 0, 0);
        s0 = __builtin_amdgcn_mfma_f32_16x16x32_f16(ka[0][1], qa[it & 3][1], s0, 0, 0, 0);
        s1 = __builtin_amdgcn_mfma_f32_16x16x32_f16(ka[1][0], qa[it & 3][0], s1, 0, 0, 0);
        s1 = __builtin_amdgcn_mfma_f32_16x16x32_f16(ka[1][1], qa[it & 3][1], s1, 0, 0, 0);
        const int nx = (it + 4 < 16) ? it + 4 : it;   // clamped depth-4 prefetch
        qa[it & 3][0] = *(const half8*)(qb + (size_t)nx * 16 * HD);
        qa[it & 3][1] = *(const half8*)(qb + (size_t)nx * 16 * HD + 32);
        #pragma unroll
        for (int r = 0; r < 4; ++r) {
            csum[0][r] += fexp2(s0[r]);
            csum[1][r] += fexp2(s1[r]);
        }
    }
    #pragma unroll
    for (int kt = 0; kt < 2; ++kt)
        #pragma unroll
        for (int r = 0; r < 4; ++r) {
            csum[kt][r] += __shfl_xor(csum[kt][r], 1);
            csum[kt][r] += __shfl_xor(csum[kt][r], 2);
            csum[kt][r] += __shfl_xor(csum[kt][r], 4);
            csum[kt][r] += __shfl_xor(csum[kt][r], 8);
        }
    if (l15 == 0) {
        #pragma unroll
        for (int kt = 0; kt < 2; ++kt)
            #pragma unroll
            for (int r = 0; r < 4; ++r)
                red[wave][kt * 16 + quad * 4 + r] = csum[kt][r];
    }
    __syncthreads();
    if (t < 32) {
        float sum = 0.f;
        #pragma unroll
        for (int w = 0; w < 8; ++w) sum += red[w][t];
        l_inv[(size_t)b * SEQ + c0 + t] = 1.0f / sum;
    }
}

// ---------------- out = P~ @ v, P~ = exp2(s~)*l_inv[key] (fp16 MFMA) ----------
// grid (64, 8) x 512 thr (8 waves). Block = 32 q-rows: rw=(w&1) row-tile,
// kw=(w>>1) key quarter (512 keys = 16 chunks of 32). Double-buffered k/li
// register prefetch; barrier-free main loop (wave-private P LDS round trip).
__global__ __launch_bounds__(512, 4) void out_kernel(
    const _Float16* __restrict__ qh, const _Float16* __restrict__ kh,
    const _Float16* __restrict__ vpt, const float* __restrict__ l_inv,
    float* __restrict__ out)
{
    __shared__ _Float16 ps[8][16][40];     // wave-private P~ (16 rows x 32 keys)
    __shared__ float red[2][3][16][68];    // per row-tile: 3 partial dumps
    __shared__ float fin[2][16][68];       // final tiles for epilogue
    const int t = threadIdx.x, lane = t & 63, wave = t >> 6;
    const int l15 = lane & 15, quad = lane >> 4;
    const int rw = wave & 1, kw = wave >> 1;
    const int b = blockIdx.y, r0 = blockIdx.x * 32;

    half8 aq[2];
    {
        const _Float16* qp = qh + ((size_t)b * SEQ + r0 + rw * 16 + l15) * HD + quad * 8;
        aq[0] = *(const half8*)(qp);
        aq[1] = *(const half8*)(qp + 32);
    }

    const size_t kbase = (size_t)b * SEQ + kw * 512;
    half8 kb[2][2][2];     // [buf][ct][kc]
    float li[2][2];        // [buf][ct]
    #pragma unroll
    for (int ct = 0; ct < 2; ++ct) {
        const _Float16* kp = kh + (kbase + ct * 16 + l15) * HD + quad * 8;
        kb[0][ct][0] = *(const half8*)(kp);
        kb[0][ct][1] = *(const half8*)(kp + 32);
        li[0][ct] = l_inv[kbase + ct * 16 + l15];
    }

    f32x4 oacc[4] = {};
    #pragma unroll 2
    for (int it = 0; it < 16; ++it) {
        const int buf = it & 1;
        const int c0k = kw * 512 + it * 32;
        if (it + 1 < 16) {   // prefetch next chunk's k + l_inv
            #pragma unroll
            for (int ct = 0; ct < 2; ++ct) {
                const _Float16* kp = kh + (kbase + (it + 1) * 32 + ct * 16 + l15) * HD + quad * 8;
                kb[buf ^ 1][ct][0] = *(const half8*)(kp);
                kb[buf ^ 1][ct][1] = *(const half8*)(kp + 32);
                li[buf ^ 1][ct] = l_inv[kbase + (it + 1) * 32 + ct * 16 + l15];
            }
        }
        // v fragments for this chunk (issued early; consumed after exp phase)
        half8 vb[4];
        #pragma unroll
        for (int n = 0; n < 4; ++n)
            vb[n] = *(const half8*)(vpt + ((size_t)b * HD + n * 16 + l15) * SEQ
                                    + c0k + quad * 8);
        // scores (16 rows x 32 keys)
        f32x4 s[2] = {};
        #pragma unroll
        for (int kc = 0; kc < 2; ++kc)
            #pragma unroll
            for (int ct = 0; ct < 2; ++ct)
                s[ct] = __builtin_amdgcn_mfma_f32_16x16x32_f16(aq[kc], kb[buf][ct][kc], s[ct], 0, 0, 0);
        // P~ = exp2(s) * l_inv -> fp16 -> wave-private LDS (C->A layout)
        #pragma unroll
        for (int ct = 0; ct < 2; ++ct)
            #pragma unroll
            for (int r = 0; r < 4; ++r)
                ps[wave][quad * 4 + r][ct * 16 + l15] =
                    (_Float16)(fexp2(s[ct][r]) * li[buf][ct]);
        half8 pa = *(half8*)&ps[wave][l15][quad * 8];
        #pragma unroll
        for (int n = 0; n < 4; ++n)
            oacc[n] = __builtin_amdgcn_mfma_f32_16x16x32_f16(pa, vb[n], oacc[n], 0, 0, 0);
    }

    // cross-wave reduction over the 4 key-quarters of each row-tile
    if (kw > 0) {
        #pragma unroll
        for (int n = 0; n < 4; ++n)
            #pragma unroll
            for (int r = 0; r < 4; ++r)
                red[rw][kw - 1][quad * 4 + r][n * 16 + l15] = oacc[n][r];
    }
    __syncthreads();
    if (kw == 0) {
        #pragma unroll
        for (int n = 0; n < 4; ++n)
            #pragma unroll
            for (int r = 0; r < 4; ++r)
                fin[rw][quad * 4 + r][n * 16 + l15] = oacc[n][r]
                    + red[rw][0][quad * 4 + r][n * 16 + l15]
                    + red[rw][1][quad * 4 + r][n * 16 + l15]
                    + red[rw][2][quad * 4 + r][n * 16 + l15];
    }
    __syncthreads();

    // epilogue: 32x64 f32 tile -> 16 head slots, coalesced float4
    const int row = t >> 4, seg = t & 15;   // 32 rows x 16 float4 segs
    float4 u = *(float4*)&fin[row >> 4][row & 15][seg * 4];
    size_t base = ((size_t)b * SEQ + r0 + row) * (HD * HEADS);
    #pragma unroll
    for (int h = 0; h < HEADS; ++h)
        *(float4*)&out[base + h * HD + seg * 4] = u;
}

extern "C" void kernel_launch(void* const* d_in, const int* in_sizes, int n_in,
                              void* d_out, int out_size, void* d_ws, size_t ws_size,
                              hipStream_t stream)
{
    const float* x  = (const float*)d_in[0];
    const float* Wq = (const float*)d_in[1];
    const float* Wk = (const float*)d_in[2];
    const float* Wv = (const float*)d_in[3];
    float* out = (float*)d_out;

    const size_t N = (size_t)BATCH * SEQ * HD;   // 1,048,576
    _Float16* qh  = (_Float16*)d_ws;
    _Float16* kh  = qh + N;
    _Float16* vpt = kh + N;
    _Float16* Wh  = vpt + N;                     // 3*64*1024 = 196608 halves
    float* l_inv  = (float*)(Wh + 196608);       // 16384 floats

    wcvt_kernel <<<dim3(32, 3),  256, 0, stream>>>(Wq, Wk, Wv, Wh);
    qkv_kernel  <<<dim3(512),    512, 0, stream>>>(x, Wh, qh, kh, vpt);
    stats_kernel<<<dim3(64, 8),  512, 0, stream>>>(qh, kh, l_inv);
    out_kernel  <<<dim3(64, 8),  512, 0, stream>>>(qh, kh, vpt, l_inv, out);
}

// Round 7
// 178.350 us; speedup vs baseline: 1.3549x; 1.3308x over previous
//
#include <hip/hip_runtime.h>

#define BATCH 8
#define SEQ   2048
#define EMB   1024
#define HD    64
#define HEADS 16
#define LOG2E 1.4426950408889634f

typedef _Float16 half8 __attribute__((ext_vector_type(8)));
typedef _Float16 half4 __attribute__((ext_vector_type(4)));
typedef float    f32x4 __attribute__((ext_vector_type(4)));

__device__ __forceinline__ float fexp2(float x) {
#if __has_builtin(__builtin_amdgcn_exp2f)
    return __builtin_amdgcn_exp2f(x);
#else
    return exp2f(x);
#endif
}

// async global->LDS DMA: lane i deposits its element at lds_base + i*size.
// lds_base must be wave-uniform; gsrc is per-lane.
__device__ __forceinline__ void dma16(void* lds_base, const void* gsrc) {
    __builtin_amdgcn_global_load_lds(
        (const __attribute__((address_space(1))) unsigned int*)gsrc,
        (__attribute__((address_space(3))) unsigned int*)lds_base, 16, 0, 0);
}
__device__ __forceinline__ void dma4(void* lds_base, const void* gsrc) {
    __builtin_amdgcn_global_load_lds(
        (const __attribute__((address_space(1))) unsigned int*)gsrc,
        (__attribute__((address_space(3))) unsigned int*)lds_base, 4, 0, 0);
}

// ---------------- W -> fp16 (Wq pre-scaled by log2e: scores in log2 domain)
__global__ __launch_bounds__(256) void wcvt_kernel(
    const float* __restrict__ Wq, const float* __restrict__ Wk,
    const float* __restrict__ Wv, _Float16* __restrict__ Wh)
{
    const int m = blockIdx.y;
    const float* src = (m == 0) ? Wq : (m == 1) ? Wk : Wv;
    const float scale = (m == 0) ? LOG2E : 1.0f;
    const int idx = (blockIdx.x * 256 + threadIdx.x) * 8;
    float4 f0 = *(const float4*)(src + idx);
    float4 f1 = *(const float4*)(src + idx + 4);
    half8 h;
    h[0] = (_Float16)(f0.x * scale); h[1] = (_Float16)(f0.y * scale);
    h[2] = (_Float16)(f0.z * scale); h[3] = (_Float16)(f0.w * scale);
    h[4] = (_Float16)(f1.x * scale); h[5] = (_Float16)(f1.y * scale);
    h[6] = (_Float16)(f1.z * scale); h[7] = (_Float16)(f1.w * scale);
    *(half8*)(Wh + (size_t)m * 65536 + idx) = h;
}

// ---------------- QKV projection ----------------
// 512 blocks x 512 thr (8 waves). Block = 32 rows, 12 ctiles; wave: strip=(w&1),
// grp=(w>>1) -> 3 ctiles. x (f32) + W (fp16) chunks staged by DMA, double-buffered,
// XOR-swizzled 16B granules; ONE vmcnt drain per chunk at the barrier.
__global__ __launch_bounds__(512) void qkv_kernel(
    const float* __restrict__ x, const _Float16* __restrict__ Wh,
    _Float16* __restrict__ qh, _Float16* __restrict__ kh, _Float16* __restrict__ vpt)
{
    __shared__ __align__(16) char arena[65536];  // x: 2x8KB, W: 2x24KB
    const int t = threadIdx.x, lane = t & 63, wave = t >> 6;
    const int l15 = lane & 15, quad = lane >> 4;
    const int strip = wave & 1, grp = wave >> 1;
    const int row0 = blockIdx.x * 32;

    auto issue = [&](int buf, int k0) {
        #pragma unroll
        for (int jj = 0; jj < 4; ++jj) {
            const int j = wave * 4 + jj;
            if (j < 8) {           // x: 8 instrs, 4 rows x 16 f32-segs each
                const int row = j * 4 + (lane >> 4);
                const int logi = (lane & 15) ^ (row & 15);
                dma16((float*)(arena + buf * 8192) + j * 256,
                      x + (size_t)(row0 + row) * EMB + k0 + logi * 4);
            } else {               // W: 24 instrs, 8 dd-rows x 8 half-segs each
                const int jw = j - 8;
                const int dd = jw * 8 + (lane >> 3);
                const int logi = (lane & 7) ^ (dd & 7);
                dma16((_Float16*)(arena + 16384 + buf * 24576) + jw * 512,
                      Wh + (size_t)(dd >> 6) * 65536 + (size_t)(dd & 63) * EMB
                         + k0 + logi * 8);
            }
        }
    };

    issue(0, 0);
    __syncthreads();

    f32x4 acc[3] = {};
    const int xrow = strip * 16 + l15;
    for (int it = 0; it < 16; ++it) {
        const int buf = it & 1;
        if (it + 1 < 16) issue(buf ^ 1, (it + 1) * 64);
        const float* xb = (const float*)(arena + buf * 8192);
        const _Float16* wb = (const _Float16*)(arena + 16384 + buf * 24576);
        half8 a[2];
        #pragma unroll
        for (int kc = 0; kc < 2; ++kc) {
            const int s0 = kc * 8 + quad * 2;
            f32x4 u0 = *(const f32x4*)(xb + xrow * 64 + ((s0    ) ^ (l15 & 15)) * 4);
            f32x4 u1 = *(const f32x4*)(xb + xrow * 64 + ((s0 + 1) ^ (l15 & 15)) * 4);
            a[kc][0] = (_Float16)u0[0]; a[kc][1] = (_Float16)u0[1];
            a[kc][2] = (_Float16)u0[2]; a[kc][3] = (_Float16)u0[3];
            a[kc][4] = (_Float16)u1[0]; a[kc][5] = (_Float16)u1[1];
            a[kc][6] = (_Float16)u1[2]; a[kc][7] = (_Float16)u1[3];
        }
        #pragma unroll
        for (int j = 0; j < 3; ++j) {
            const int dd = (grp * 3 + j) * 16 + l15;
            #pragma unroll
            for (int kc = 0; kc < 2; ++kc) {
                half8 bfr = *(const half8*)(wb + dd * 64
                              + (((kc * 4 + quad) ^ (l15 & 7)) * 8));
                acc[j] = __builtin_amdgcn_mfma_f32_16x16x32_f16(a[kc], bfr, acc[j], 0, 0, 0);
            }
        }
        __syncthreads();
    }

    #pragma unroll
    for (int j = 0; j < 3; ++j) {
        const int c = grp * 3 + j, m = c >> 2, n = c & 3;
        if (m < 2) {
            _Float16* __restrict__ dst = (m == 0) ? qh : kh;
            #pragma unroll
            for (int r = 0; r < 4; ++r)
                dst[(size_t)(row0 + strip * 16 + quad * 4 + r) * HD + n * 16 + l15] =
                    (_Float16)acc[j][r];
        } else {
            const int rg = row0 + strip * 16 + quad * 4;
            const int b = rg >> 11, s = rg & 2047;
            half4 h;
            h[0] = (_Float16)acc[j][0]; h[1] = (_Float16)acc[j][1];
            h[2] = (_Float16)acc[j][2]; h[3] = (_Float16)acc[j][3];
            *(half4*)(vpt + ((size_t)b * HD + n * 16 + l15) * SEQ + s) = h;
        }
    }
}

// ---------------- Column-softmax denominators ----------------
// grid (64,8) x 256 thr (4 waves). Block = 32 keys (A-frags held in regs);
// queries streamed in 32 DMA'd chunks of 64; wave w -> queries w*16 of each chunk.
__global__ __launch_bounds__(256) void stats_kernel(
    const _Float16* __restrict__ qh, const _Float16* __restrict__ kh,
    float* __restrict__ l_inv)
{
    __shared__ __align__(16) char arena[16384];  // q: 2x8KB
    __shared__ float red[4][32];
    const int t = threadIdx.x, lane = t & 63, wave = t >> 6;
    const int l15 = lane & 15, quad = lane >> 4;
    const int b = blockIdx.y, c0 = blockIdx.x * 32;

    half8 ka[2][2];
    #pragma unroll
    for (int kt = 0; kt < 2; ++kt) {
        const _Float16* kp = kh + ((size_t)b * SEQ + c0 + kt * 16 + l15) * HD + quad * 8;
        ka[kt][0] = *(const half8*)(kp);
        ka[kt][1] = *(const half8*)(kp + 32);
    }

    auto issue = [&](int buf, int q0) {
        #pragma unroll
        for (int jj = 0; jj < 2; ++jj) {
            const int j = wave * 2 + jj;
            const int qq = j * 8 + (lane >> 3);
            const int logi = (lane & 7) ^ (qq & 7);
            dma16((_Float16*)(arena + buf * 8192) + j * 512,
                  qh + ((size_t)b * SEQ + q0 + qq) * HD + logi * 8);
        }
    };

    issue(0, 0);
    __syncthreads();

    float csum[2][4] = {};
    const int qrow = wave * 16 + l15;
    for (int it = 0; it < 32; ++it) {
        const int buf = it & 1;
        if (it + 1 < 32) issue(buf ^ 1, (it + 1) * 64);
        const _Float16* qb = (const _Float16*)(arena + buf * 8192);
        half8 bq[2];
        #pragma unroll
        for (int kc = 0; kc < 2; ++kc)
            bq[kc] = *(const half8*)(qb + qrow * 64
                        + (((kc * 4 + quad) ^ (l15 & 7)) * 8));
        f32x4 s0 = {}, s1 = {};
        s0 = __builtin_amdgcn_mfma_f32_16x16x32_f16(ka[0][0], bq[0], s0, 0, 0, 0);
        s0 = __builtin_amdgcn_mfma_f32_16x16x32_f16(ka[0][1], bq[1], s0, 0, 0, 0);
        s1 = __builtin_amdgcn_mfma_f32_16x16x32_f16(ka[1][0], bq[0], s1, 0, 0, 0);
        s1 = __builtin_amdgcn_mfma_f32_16x16x32_f16(ka[1][1], bq[1], s1, 0, 0, 0);
        #pragma unroll
        for (int r = 0; r < 4; ++r) {
            csum[0][r] += fexp2(s0[r]);
            csum[1][r] += fexp2(s1[r]);
        }
        __syncthreads();
    }
    #pragma unroll
    for (int kt = 0; kt < 2; ++kt)
        #pragma unroll
        for (int r = 0; r < 4; ++r) {
            csum[kt][r] += __shfl_xor(csum[kt][r], 1);
            csum[kt][r] += __shfl_xor(csum[kt][r], 2);
            csum[kt][r] += __shfl_xor(csum[kt][r], 4);
            csum[kt][r] += __shfl_xor(csum[kt][r], 8);
        }
    if (l15 == 0) {
        #pragma unroll
        for (int kt = 0; kt < 2; ++kt)
            #pragma unroll
            for (int r = 0; r < 4; ++r)
                red[wave][kt * 16 + quad * 4 + r] = csum[kt][r];
    }
    __syncthreads();
    if (t < 32)
        l_inv[(size_t)b * SEQ + c0 + t] =
            1.0f / (red[0][t] + red[1][t] + red[2][t] + red[3][t]);
}

// ---------------- out = P~ @ v, P~ = exp2(s~)*l_inv[key] ----------------
// grid (64,8) x 256 thr (4 waves): rw=(w&1) row-tile, kw=(w>>1) key-half.
// Block = 32 q-rows x all keys; 32 chunks of 64 keys, k/v/l_inv DMA'd,
// double-buffered, swizzled. Wave-private P LDS round trip. Cross-wave O
// reduction + x16-head coalesced epilogue (overlaid on staging LDS).
__global__ __launch_bounds__(256) void out_kernel(
    const _Float16* __restrict__ qh, const _Float16* __restrict__ kh,
    const _Float16* __restrict__ vpt, const float* __restrict__ l_inv,
    float* __restrict__ out)
{
    __shared__ __align__(16) char arena[38400];
    // [0,16384)      kbuf  [2][64][64] fp16
    // [16384,32768)  vbuf  [2][64][64] fp16
    // [32768,33280)  lbuf  [2][64] f32
    // [33280,38400)  ps    [4][16][40] fp16
    const int t = threadIdx.x, lane = t & 63, wave = t >> 6;
    const int l15 = lane & 15, quad = lane >> 4;
    const int rw = wave & 1, kw = wave >> 1;
    const int b = blockIdx.y, r0 = blockIdx.x * 32;

    half8 aq[2];
    {
        const _Float16* qp = qh + ((size_t)b * SEQ + r0 + rw * 16 + l15) * HD + quad * 8;
        aq[0] = *(const half8*)(qp);
        aq[1] = *(const half8*)(qp + 32);
    }

    auto issue = [&](int buf, int c0) {
        #pragma unroll
        for (int jj = 0; jj < 4; ++jj) {
            if (wave < 2) {        // k: 8 instrs
                const int j = wave * 4 + jj;
                const int key = j * 8 + (lane >> 3);
                const int logi = (lane & 7) ^ (key & 7);
                dma16((_Float16*)(arena + buf * 8192) + j * 512,
                      kh + ((size_t)b * SEQ + c0 + key) * HD + logi * 8);
            } else {               // v: 8 instrs (vpt is [b][d][s])
                const int j = (wave - 2) * 4 + jj;
                const int d = j * 8 + (lane >> 3);
                const int logi = (lane & 7) ^ (d & 7);
                dma16((_Float16*)(arena + 16384 + buf * 8192) + j * 512,
                      vpt + ((size_t)b * HD + d) * SEQ + c0 + logi * 8);
            }
        }
        if (wave == 0)
            dma4((float*)(arena + 32768) + buf * 64,
                 l_inv + (size_t)b * SEQ + c0 + lane);
    };

    issue(0, 0);
    __syncthreads();

    _Float16* psb = (_Float16*)(arena + 33280) + wave * 640;
    f32x4 oacc[4] = {};
    for (int it = 0; it < 32; ++it) {
        const int buf = it & 1;
        if (it + 1 < 32) issue(buf ^ 1, (it + 1) * 64);
        const _Float16* kb = (const _Float16*)(arena + buf * 8192);
        const _Float16* vb = (const _Float16*)(arena + 16384 + buf * 8192);
        const float*    lb = (const float*)(arena + 32768) + buf * 64;

        f32x4 s[2] = {};
        float li[2];
        #pragma unroll
        for (int ct = 0; ct < 2; ++ct) {
            const int key = kw * 32 + ct * 16 + l15;
            li[ct] = lb[key];
            #pragma unroll
            for (int kc = 0; kc < 2; ++kc) {
                half8 kf = *(const half8*)(kb + key * 64
                             + (((kc * 4 + quad) ^ (l15 & 7)) * 8));
                s[ct] = __builtin_amdgcn_mfma_f32_16x16x32_f16(aq[kc], kf, s[ct], 0, 0, 0);
            }
        }
        #pragma unroll
        for (int ct = 0; ct < 2; ++ct)
            #pragma unroll
            for (int r = 0; r < 4; ++r)
                psb[(quad * 4 + r) * 40 + ct * 16 + l15] =
                    (_Float16)(fexp2(s[ct][r]) * li[ct]);
        half8 pa = *(const half8*)(psb + l15 * 40 + quad * 8);
        #pragma unroll
        for (int n = 0; n < 4; ++n) {
            const int d = n * 16 + l15;
            half8 vf = *(const half8*)(vb + d * 64
                         + (((kw * 4 + quad) ^ (l15 & 7)) * 8));
            oacc[n] = __builtin_amdgcn_mfma_f32_16x16x32_f16(pa, vf, oacc[n], 0, 0, 0);
        }
        __syncthreads();
    }

    // cross-wave (key-half) reduction; overlay red/fin on the staging area
    float* red = (float*)(arena);            // [2][16][68]
    float* fin = (float*)(arena + 8704);     // [2][16][68] == [32][68]
    if (kw == 1) {
        #pragma unroll
        for (int n = 0; n < 4; ++n)
            #pragma unroll
            for (int r = 0; r < 4; ++r)
                red[(rw * 16 + quad * 4 + r) * 68 + n * 16 + l15] = oacc[n][r];
    }
    __syncthreads();
    if (kw == 0) {
        #pragma unroll
        for (int n = 0; n < 4; ++n)
            #pragma unroll
            for (int r = 0; r < 4; ++r)
                fin[(rw * 16 + quad * 4 + r) * 68 + n * 16 + l15] =
                    oacc[n][r] + red[(rw * 16 + quad * 4 + r) * 68 + n * 16 + l15];
    }
    __syncthreads();

    // epilogue: 32x64 f32 tile -> 16 head slots, coalesced float4
    const int row = t >> 3, s8 = t & 7;
    float4 u0 = *(float4*)(fin + row * 68 + s8 * 8);
    float4 u1 = *(float4*)(fin + row * 68 + s8 * 8 + 4);
    size_t base = ((size_t)b * SEQ + r0 + row) * (HD * HEADS);
    #pragma unroll
    for (int h = 0; h < HEADS; ++h) {
        *(float4*)&out[base + h * HD + s8 * 8]     = u0;
        *(float4*)&out[base + h * HD + s8 * 8 + 4] = u1;
    }
}

extern "C" void kernel_launch(void* const* d_in, const int* in_sizes, int n_in,
                              void* d_out, int out_size, void* d_ws, size_t ws_size,
                              hipStream_t stream)
{
    const float* x  = (const float*)d_in[0];
    const float* Wq = (const float*)d_in[1];
    const float* Wk = (const float*)d_in[2];
    const float* Wv = (const float*)d_in[3];
    float* out = (float*)d_out;

    const size_t N = (size_t)BATCH * SEQ * HD;   // 1,048,576
    _Float16* qh  = (_Float16*)d_ws;
    _Float16* kh  = qh + N;
    _Float16* vpt = kh + N;
    _Float16* Wh  = vpt + N;                     // 3*64*1024 halves
    float* l_inv  = (float*)(Wh + 196608);

    wcvt_kernel <<<dim3(32, 3), 256, 0, stream>>>(Wq, Wk, Wv, Wh);
    qkv_kernel  <<<dim3(512),   512, 0, stream>>>(x, Wh, qh, kh, vpt);
    stats_kernel<<<dim3(64, 8), 256, 0, stream>>>(qh, kh, l_inv);
    out_kernel  <<<dim3(64, 8), 256, 0, stream>>>(qh, kh, vpt, l_inv, out);
}